// Round 5
// baseline (479.712 us; speedup 1.0000x reference)
//
#include <hip/hip_runtime.h>

// LightGCN layer: out[d] = in_deg[d]^-1/2 * sum_{e:dst[e]=d} x[src[e]] * out_deg[src[e]]^-1/2
//
// Round 5: replace global-atomic binning (86 us, atomic-latency-bound) with
// node-range-partitioned LDS binning:
//   - prepack: pk[i] = dst|src<<16 (one 4B word per edge, 3.2 MB total)
//   - scanbin: 125 blocks x 400 nodes; each block scans the whole pk array
//     (L2-resident), bins dst-matches into LDS slots via LDS atomics,
//     histograms src-matches into LDS counters. Coalesced write-out.
//     No global atomics except rare deg>CAP overflow.
// Gather (round 4): bf16 pre-scaled xs rows, readlane src broadcast.

#define D_FEAT 96
#define CAP 64
#define RNODES 400
#define OVF_CAP 8192

__device__ __forceinline__ unsigned short f2bf_rne(float f) {
    unsigned u = __float_as_uint(f);
    unsigned r = (u >> 16) & 1u;
    u += 0x7fffu + r;
    return (unsigned short)(u >> 16);
}

// ---------------- main path ----------------

__global__ void prepack_kernel(const int* __restrict__ src,
                               const int* __restrict__ dst,
                               unsigned* __restrict__ pk, int n_edges) {
    int i = blockIdx.x * blockDim.x + threadIdx.x;
    if (i < n_edges)
        pk[i] = (unsigned)dst[i] | ((unsigned)src[i] << 16);
}

__global__ __launch_bounds__(256) void scanbin_kernel(
        const unsigned* __restrict__ pk, int n_edges, int n_nodes,
        int* __restrict__ out_cnt, int* __restrict__ cursor,
        unsigned short* __restrict__ slots, int* __restrict__ ovf) {
    __shared__ int lcnt_in[RNODES];
    __shared__ int lcnt_out[RNODES];
    __shared__ unsigned short lslots[RNODES * CAP];

    const int base = blockIdx.x * RNODES;
    const int nloc = min(RNODES, n_nodes - base);

    for (int i = threadIdx.x; i < RNODES; i += 256) { lcnt_in[i] = 0; lcnt_out[i] = 0; }
    __syncthreads();

    const int n4 = n_edges >> 2;
    const uint4* pk4 = (const uint4*)pk;
    const unsigned un = (unsigned)nloc;

    for (int i = threadIdx.x; i < n4; i += 256) {
        uint4 u = pk4[i];
        #pragma unroll
        for (int j = 0; j < 4; ++j) {
            unsigned v = (j == 0) ? u.x : (j == 1) ? u.y : (j == 2) ? u.z : u.w;
            int d = (int)(v & 0xffffu);
            int s = (int)(v >> 16);
            unsigned sl = (unsigned)(s - base);
            if (sl < un) atomicAdd(&lcnt_out[sl], 1);
            unsigned dl = (unsigned)(d - base);
            if (dl < un) {
                int pos = atomicAdd(&lcnt_in[dl], 1);
                if (pos < CAP) {
                    lslots[dl * CAP + pos] = (unsigned short)s;
                } else {
                    int k = atomicAdd(&ovf[0], 1);
                    if (k < OVF_CAP) ovf[1 + k] = i * 4 + j;
                }
            }
        }
    }
    // scalar tail (n_edges % 4)
    for (int i = (n4 << 2) + threadIdx.x; i < n_edges; i += 256) {
        unsigned v = pk[i];
        int d = (int)(v & 0xffffu);
        int s = (int)(v >> 16);
        unsigned sl = (unsigned)(s - base);
        if (sl < un) atomicAdd(&lcnt_out[sl], 1);
        unsigned dl = (unsigned)(d - base);
        if (dl < un) {
            int pos = atomicAdd(&lcnt_in[dl], 1);
            if (pos < CAP) lslots[dl * CAP + pos] = (unsigned short)s;
            else { int k = atomicAdd(&ovf[0], 1); if (k < OVF_CAP) ovf[1 + k] = i; }
        }
    }
    __syncthreads();

    for (int i = threadIdx.x; i < nloc; i += 256) {
        cursor[base + i]  = lcnt_in[i];    // true in-degree (incl. overflow)
        out_cnt[base + i] = lcnt_out[i];
    }
    // coalesced slot copy (garbage beyond cnt is never read)
    const unsigned* ls = (const unsigned*)lslots;
    unsigned* gs = (unsigned*)slots + (size_t)base * (CAP / 2);
    const int ncopy = nloc * (CAP / 2);
    for (int i = threadIdx.x; i < ncopy; i += 256) gs[i] = ls[i];
}

// xs[node*48 + j] = pack2bf16(x[node*96+2j]*w, x[node*96+2j+1]*w), w = out_deg^-1/2
__global__ void convert_kernel(const float* __restrict__ x,
                               const int* __restrict__ out_cnt,
                               unsigned* __restrict__ xs, int n_total) {
    int t = blockIdx.x * blockDim.x + threadIdx.x;
    if (t >= n_total) return;
    int node = t / 48;
    int j = t - node * 48;
    int c = out_cnt[node];
    float w = rsqrtf((float)(c < 1 ? 1 : c));
    float2 v = *(const float2*)(x + (size_t)node * D_FEAT + j * 2);
    unsigned lo = f2bf_rne(v.x * w);
    unsigned hi = f2bf_rne(v.y * w);
    xs[t] = lo | (hi << 16);
}

__global__ __launch_bounds__(256) void gather_kernel(
        const unsigned* __restrict__ xs,          // [n_nodes*48] packed bf16 pairs
        const unsigned short* __restrict__ slots,
        const int* __restrict__ cursor,
        float* __restrict__ out, int n_nodes) {
    int wid  = threadIdx.x >> 6;
    int lane = threadIdx.x & 63;
    int node = __builtin_amdgcn_readfirstlane(blockIdx.x * 4 + wid);
    if (node >= n_nodes) return;

    int cnt_all = __builtin_amdgcn_readfirstlane(cursor[node]);
    int cnt = cnt_all < CAP ? cnt_all : CAP;

    float2 acc = make_float2(0.f, 0.f);
    const bool act = lane < 48;        // 48 lanes x (2 bf16) = 96 features

    if (cnt > 0) {
        int idx  = lane < cnt ? lane : cnt - 1;
        int sval = (int)slots[node * CAP + idx];   // lane l holds slot l's src id

        int e = 0;
        for (; e + 8 <= cnt; e += 8) {
            int s0 = __builtin_amdgcn_readlane(sval, e);
            int s1 = __builtin_amdgcn_readlane(sval, e + 1);
            int s2 = __builtin_amdgcn_readlane(sval, e + 2);
            int s3 = __builtin_amdgcn_readlane(sval, e + 3);
            int s4 = __builtin_amdgcn_readlane(sval, e + 4);
            int s5 = __builtin_amdgcn_readlane(sval, e + 5);
            int s6 = __builtin_amdgcn_readlane(sval, e + 6);
            int s7 = __builtin_amdgcn_readlane(sval, e + 7);
            if (act) {
                unsigned u0 = xs[s0 * 48 + lane];
                unsigned u1 = xs[s1 * 48 + lane];
                unsigned u2 = xs[s2 * 48 + lane];
                unsigned u3 = xs[s3 * 48 + lane];
                unsigned u4 = xs[s4 * 48 + lane];
                unsigned u5 = xs[s5 * 48 + lane];
                unsigned u6 = xs[s6 * 48 + lane];
                unsigned u7 = xs[s7 * 48 + lane];
                acc.x += __uint_as_float(u0 << 16); acc.y += __uint_as_float(u0 & 0xffff0000u);
                acc.x += __uint_as_float(u1 << 16); acc.y += __uint_as_float(u1 & 0xffff0000u);
                acc.x += __uint_as_float(u2 << 16); acc.y += __uint_as_float(u2 & 0xffff0000u);
                acc.x += __uint_as_float(u3 << 16); acc.y += __uint_as_float(u3 & 0xffff0000u);
                acc.x += __uint_as_float(u4 << 16); acc.y += __uint_as_float(u4 & 0xffff0000u);
                acc.x += __uint_as_float(u5 << 16); acc.y += __uint_as_float(u5 & 0xffff0000u);
                acc.x += __uint_as_float(u6 << 16); acc.y += __uint_as_float(u6 & 0xffff0000u);
                acc.x += __uint_as_float(u7 << 16); acc.y += __uint_as_float(u7 & 0xffff0000u);
            }
        }
        for (; e + 4 <= cnt; e += 4) {
            int s0 = __builtin_amdgcn_readlane(sval, e);
            int s1 = __builtin_amdgcn_readlane(sval, e + 1);
            int s2 = __builtin_amdgcn_readlane(sval, e + 2);
            int s3 = __builtin_amdgcn_readlane(sval, e + 3);
            if (act) {
                unsigned u0 = xs[s0 * 48 + lane];
                unsigned u1 = xs[s1 * 48 + lane];
                unsigned u2 = xs[s2 * 48 + lane];
                unsigned u3 = xs[s3 * 48 + lane];
                acc.x += __uint_as_float(u0 << 16); acc.y += __uint_as_float(u0 & 0xffff0000u);
                acc.x += __uint_as_float(u1 << 16); acc.y += __uint_as_float(u1 & 0xffff0000u);
                acc.x += __uint_as_float(u2 << 16); acc.y += __uint_as_float(u2 & 0xffff0000u);
                acc.x += __uint_as_float(u3 << 16); acc.y += __uint_as_float(u3 & 0xffff0000u);
            }
        }
        for (; e < cnt; ++e) {
            int s0 = __builtin_amdgcn_readlane(sval, e);
            if (act) {
                unsigned u0 = xs[s0 * 48 + lane];
                acc.x += __uint_as_float(u0 << 16); acc.y += __uint_as_float(u0 & 0xffff0000u);
            }
        }
    }

    float sc = rsqrtf((float)(cnt_all < 1 ? 1 : cnt_all));
    if (act) {
        float2 r = make_float2(acc.x * sc, acc.y * sc);
        *(float2*)(out + (size_t)node * D_FEAT + lane * 2) = r;
    }
}

// Fix up edges that overflowed CAP (adds on top of gather's output). Uses fp32 x.
__global__ void overflow_kernel(const float* __restrict__ x,
                                const int* __restrict__ src,
                                const int* __restrict__ dst,
                                const int* __restrict__ out_cnt,
                                const int* __restrict__ cursor,
                                const int* __restrict__ ovf,
                                float* __restrict__ out) {
    int count = ovf[0];
    if (count > OVF_CAP) count = OVF_CAP;
    int total = count * 24;
    int stride = gridDim.x * blockDim.x;
    for (int i = blockIdx.x * blockDim.x + threadIdx.x; i < total; i += stride) {
        int k = i / 24, c = i % 24;
        int e = ovf[1 + k];
        int s = src[e], d = dst[e];
        int co = out_cnt[s], ci = cursor[d];
        float w = rsqrtf((float)(co < 1 ? 1 : co)) * rsqrtf((float)(ci < 1 ? 1 : ci));
        const float4 v = *(const float4*)(x + (size_t)s * D_FEAT + c * 4);
        float* o = out + (size_t)d * D_FEAT + c * 4;
        unsafeAtomicAdd(o + 0, v.x * w);
        unsafeAtomicAdd(o + 1, v.y * w);
        unsafeAtomicAdd(o + 2, v.z * w);
        unsafeAtomicAdd(o + 3, v.w * w);
    }
}

// ---------------- fallback (round-1 atomic scatter) ----------------

__global__ void degree_kernel(const int* __restrict__ src,
                              const int* __restrict__ dst,
                              int* __restrict__ out_cnt,
                              int* __restrict__ in_cnt,
                              int n_edges) {
    int i = blockIdx.x * blockDim.x + threadIdx.x;
    if (i < n_edges) {
        atomicAdd(&out_cnt[src[i]], 1);
        atomicAdd(&in_cnt[dst[i]], 1);
    }
}

__global__ void scale_kernel(float* __restrict__ osc, float* __restrict__ isc, int n) {
    int i = blockIdx.x * blockDim.x + threadIdx.x;
    if (i < n) {
        int c0 = ((const int*)osc)[i];
        int c1 = ((const int*)isc)[i];
        osc[i] = rsqrtf((float)(c0 < 1 ? 1 : c0));
        isc[i] = rsqrtf((float)(c1 < 1 ? 1 : c1));
    }
}

__global__ void scatter_kernel(const float* __restrict__ x,
                               const int* __restrict__ src,
                               const int* __restrict__ dst,
                               const float* __restrict__ osc,
                               const float* __restrict__ isc,
                               float* __restrict__ out, int n_edges) {
    int idx = blockIdx.x * blockDim.x + threadIdx.x;
    int e = idx / 24;
    int c = idx % 24;
    if (e >= n_edges) return;
    int s = src[e], d = dst[e];
    float w = osc[s] * isc[d];
    const float4 v = *(const float4*)(x + (size_t)s * D_FEAT + c * 4);
    float* o = out + (size_t)d * D_FEAT + c * 4;
    unsafeAtomicAdd(o + 0, v.x * w);
    unsafeAtomicAdd(o + 1, v.y * w);
    unsafeAtomicAdd(o + 2, v.z * w);
    unsafeAtomicAdd(o + 3, v.w * w);
}

// ---------------- launcher ----------------

extern "C" void kernel_launch(void* const* d_in, const int* in_sizes, int n_in,
                              void* d_out, int out_size, void* d_ws, size_t ws_size,
                              hipStream_t stream) {
    const float* x  = (const float*)d_in[0];
    const int* src  = (const int*)d_in[1];
    const int* dst  = (const int*)d_in[2];
    float* out      = (float*)d_out;

    const int n_edges = in_sizes[1];
    const int n_nodes = in_sizes[0] / D_FEAT;

    // ws layout (int32 offsets):
    //   [0]        out_cnt   (65536)
    //   [65536]    cursor    (65536)
    //   [131072]   ovf       (1 + OVF_CAP, pad to 8200)
    //   [139272]   pk        (n_edges uints, dst|src<<16)
    //   [+n_edges] xs        (n_nodes * 48 uints, packed bf16 pairs)
    //   [+...]     slots     (n_nodes * CAP ushorts)
    int* out_cnt = (int*)d_ws;
    int* cursor  = out_cnt + 65536;
    int* ovf     = out_cnt + 131072;
    unsigned* pk = (unsigned*)(out_cnt + 139272);
    unsigned* xs = pk + n_edges;
    unsigned short* slots = (unsigned short*)(xs + (size_t)n_nodes * 48);

    const size_t needed =
        ((size_t)139272 + (size_t)n_edges + (size_t)n_nodes * 48 +
         (size_t)n_nodes * (CAP / 2)) * 4;

    if (ws_size >= needed && n_nodes <= 65536) {
        // only ovf[0] needs zeroing (counts/cursors written wholesale by scanbin)
        hipMemsetAsync(ovf, 0, sizeof(int), stream);

        prepack_kernel<<<(n_edges + 255) / 256, 256, 0, stream>>>(
            src, dst, pk, n_edges);

        const int nblk = (n_nodes + RNODES - 1) / RNODES;
        scanbin_kernel<<<nblk, 256, 0, stream>>>(
            pk, n_edges, n_nodes, out_cnt, cursor, slots, ovf);

        const int n_pairs = n_nodes * 48;
        convert_kernel<<<(n_pairs + 255) / 256, 256, 0, stream>>>(
            x, out_cnt, xs, n_pairs);

        gather_kernel<<<(n_nodes + 3) / 4, 256, 0, stream>>>(
            xs, slots, cursor, out, n_nodes);

        overflow_kernel<<<32, 256, 0, stream>>>(
            x, src, dst, out_cnt, cursor, ovf, out);
    } else {
        // fallback: atomic scatter (round-1 path)
        float* osc = (float*)d_ws;
        float* isc = osc + 65536;
        hipMemsetAsync(d_ws, 0, 2 * 65536 * sizeof(int), stream);
        hipMemsetAsync(d_out, 0, (size_t)out_size * sizeof(float), stream);
        degree_kernel<<<(n_edges + 255) / 256, 256, 0, stream>>>(
            src, dst, (int*)osc, (int*)isc, n_edges);
        scale_kernel<<<(n_nodes + 255) / 256, 256, 0, stream>>>(osc, isc, n_nodes);
        const int total = n_edges * 24;
        scatter_kernel<<<(total + 255) / 256, 256, 0, stream>>>(
            x, src, dst, osc, isc, out, n_edges);
    }
}

// Round 6
// 143.419 us; speedup vs baseline: 3.3448x; 3.3448x over previous
//
#include <hip/hip_runtime.h>

// LightGCN layer: out[d] = in_deg[d]^-1/2 * sum_{e:dst[e]=d} x[src[e]] * out_deg[src[e]]^-1/2
//
// Round 6: two-pass multisplit binning (fixes round 5's 125x-redundant scan and
// round 4's 1.6M global atomics):
//   pass 1 (partition): blocks of 4096 edges LDS-histogram by dst>>8 and src>>8,
//     reserve per-partition space with ONE global atomic per partition per block
//     (~38k total), scatter packed edges into per-partition buffers (dense ->
//     L2 write-combines full lines).
//   pass 2 (bin2/cnt2): block b reads ONLY partition b (~4k edges), LDS-atomic
//     bins into a 256-node x 64-slot tile / histograms src counts. Coalesced
//     write-out. 33 KB LDS -> 4 blocks/CU.
// Gather (round 4): bf16 pre-scaled xs rows, readlane src broadcast.

#define D_FEAT 96
#define CAP 64
#define PART_SHIFT 8
#define PNODES 256
#define NP_MAX 256
#define EPB 4096
#define OVF_CAP 8192

__device__ __forceinline__ unsigned short f2bf_rne(float f) {
    unsigned u = __float_as_uint(f);
    unsigned r = (u >> 16) & 1u;
    u += 0x7fffu + r;
    return (unsigned short)(u >> 16);
}

// ---------------- pass 1: partition ----------------

__global__ __launch_bounds__(256) void partition_kernel(
        const int* __restrict__ src, const int* __restrict__ dst,
        int n_edges, int np, int stride,
        int* __restrict__ pcur_d, int* __restrict__ pcur_s,
        unsigned* __restrict__ pbuf_d, unsigned short* __restrict__ pbuf_s,
        int* __restrict__ ctr,            // [0]=ovf_n [1]=povf_n [2]=sovf_n
        int* __restrict__ povf_d, int* __restrict__ sovf_d) {
    __shared__ int hcd[NP_MAX], hcs[NP_MAX];
    __shared__ int bd[NP_MAX], bs_[NP_MAX];
    __shared__ int od[NP_MAX], os_[NP_MAX];
    const int base = blockIdx.x * EPB;

    for (int i = threadIdx.x; i < NP_MAX; i += 256) {
        hcd[i] = 0; hcs[i] = 0; od[i] = 0; os_[i] = 0;
    }
    __syncthreads();

    unsigned v[16];
    #pragma unroll
    for (int k = 0; k < 16; ++k) {
        int i = base + (int)threadIdx.x + (k << 8);
        if (i < n_edges) {
            int s = src[i], d = dst[i];
            unsigned pv = (unsigned)d | ((unsigned)s << 16);
            v[k] = pv;
            atomicAdd(&hcd[d >> PART_SHIFT], 1);
            atomicAdd(&hcs[s >> PART_SHIFT], 1);
        }
    }
    __syncthreads();

    for (int p = threadIdx.x; p < np; p += 256) {
        int cd = hcd[p];
        bd[p] = cd ? atomicAdd(&pcur_d[p], cd) : 0;
        int cs = hcs[p];
        bs_[p] = cs ? atomicAdd(&pcur_s[p], cs) : 0;
    }
    __syncthreads();

    #pragma unroll
    for (int k = 0; k < 16; ++k) {
        int i = base + (int)threadIdx.x + (k << 8);
        if (i < n_edges) {
            unsigned pv = v[k];
            int d = (int)(pv & 0xffffu);
            int s = (int)(pv >> 16);
            int pd = d >> PART_SHIFT;
            int j = bd[pd] + atomicAdd(&od[pd], 1);
            if (j < stride) pbuf_d[(size_t)pd * stride + j] = pv;
            else { int k2 = atomicAdd(&ctr[1], 1); if (k2 < OVF_CAP) povf_d[k2] = (int)pv; }
            int ps = s >> PART_SHIFT;
            int j2 = bs_[ps] + atomicAdd(&os_[ps], 1);
            if (j2 < stride) pbuf_s[(size_t)ps * stride + j2] = (unsigned short)s;
            else { int k3 = atomicAdd(&ctr[2], 1); if (k3 < OVF_CAP) sovf_d[k3] = s; }
        }
    }
}

// ---------------- pass 2: bin dst side ----------------

__global__ __launch_bounds__(256) void bin2_kernel(
        const unsigned* __restrict__ pbuf_d, const int* __restrict__ pcur_d,
        int stride, int n_nodes,
        int* __restrict__ cursor, unsigned short* __restrict__ slots,
        int* __restrict__ ctr, int* __restrict__ ovf_d) {
    __shared__ unsigned short lslots[PNODES * CAP];   // 32 KB
    __shared__ int lcnt[PNODES];
    const int b = blockIdx.x;
    const int nbase = b << PART_SHIFT;
    const int nloc = min(PNODES, n_nodes - nbase);

    for (int i = threadIdx.x; i < PNODES; i += 256) lcnt[i] = 0;
    __syncthreads();

    int n = pcur_d[b]; if (n > stride) n = stride;
    for (int i = threadIdx.x; i < n; i += 256) {
        unsigned pv = pbuf_d[(size_t)b * stride + i];
        int dl = (int)(pv & 0xffu);        // d - nbase (partition is 256-aligned)
        int s  = (int)(pv >> 16);
        int pos = atomicAdd(&lcnt[dl], 1);
        if (pos < CAP) lslots[dl * CAP + pos] = (unsigned short)s;
        else { int k = atomicAdd(&ctr[0], 1); if (k < OVF_CAP) ovf_d[k] = (int)pv; }
    }
    __syncthreads();

    for (int i = threadIdx.x; i < nloc; i += 256) cursor[nbase + i] = lcnt[i];
    const unsigned* ls = (const unsigned*)lslots;
    unsigned* gs = (unsigned*)slots + (size_t)nbase * (CAP / 2);
    const int ncopy = nloc * (CAP / 2);
    for (int i = threadIdx.x; i < ncopy; i += 256) gs[i] = ls[i];
}

// ---------------- pass 2: count src side ----------------

__global__ __launch_bounds__(256) void cnt2_kernel(
        const unsigned short* __restrict__ pbuf_s, const int* __restrict__ pcur_s,
        int stride, int n_nodes, int* __restrict__ out_cnt) {
    __shared__ int lcnt[PNODES];
    const int b = blockIdx.x;
    const int nbase = b << PART_SHIFT;
    const int nloc = min(PNODES, n_nodes - nbase);

    for (int i = threadIdx.x; i < PNODES; i += 256) lcnt[i] = 0;
    __syncthreads();

    int n = pcur_s[b]; if (n > stride) n = stride;
    for (int i = threadIdx.x; i < n; i += 256) {
        int s = (int)pbuf_s[(size_t)b * stride + i];
        atomicAdd(&lcnt[s & (PNODES - 1)], 1);
    }
    __syncthreads();

    for (int i = threadIdx.x; i < nloc; i += 256) out_cnt[nbase + i] = lcnt[i];
}

// Exactness fixup for (statistically impossible) partition-buffer overflow.
__global__ void fixup_kernel(int* __restrict__ ctr,
                             const int* __restrict__ povf_d,
                             const int* __restrict__ sovf_d,
                             int* __restrict__ ovf_d,
                             int* __restrict__ cursor,
                             int* __restrict__ out_cnt) {
    int np_ = ctr[1]; if (np_ > OVF_CAP) np_ = OVF_CAP;
    for (int i = threadIdx.x; i < np_; i += 256) {
        unsigned pv = (unsigned)povf_d[i];
        atomicAdd(&cursor[pv & 0xffffu], 1);
        int k = atomicAdd(&ctr[0], 1);
        if (k < OVF_CAP) ovf_d[k] = (int)pv;
    }
    int ns_ = ctr[2]; if (ns_ > OVF_CAP) ns_ = OVF_CAP;
    for (int i = threadIdx.x; i < ns_; i += 256)
        atomicAdd(&out_cnt[(unsigned)sovf_d[i]], 1);
}

// ---------------- convert + gather (round 4, proven) ----------------

__global__ void convert_kernel(const float* __restrict__ x,
                               const int* __restrict__ out_cnt,
                               unsigned* __restrict__ xs, int n_total) {
    int t = blockIdx.x * blockDim.x + threadIdx.x;
    if (t >= n_total) return;
    int node = t / 48;
    int j = t - node * 48;
    int c = out_cnt[node];
    float w = rsqrtf((float)(c < 1 ? 1 : c));
    float2 v = *(const float2*)(x + (size_t)node * D_FEAT + j * 2);
    unsigned lo = f2bf_rne(v.x * w);
    unsigned hi = f2bf_rne(v.y * w);
    xs[t] = lo | (hi << 16);
}

__global__ __launch_bounds__(256) void gather_kernel(
        const unsigned* __restrict__ xs,
        const unsigned short* __restrict__ slots,
        const int* __restrict__ cursor,
        float* __restrict__ out, int n_nodes) {
    int wid  = threadIdx.x >> 6;
    int lane = threadIdx.x & 63;
    int node = __builtin_amdgcn_readfirstlane(blockIdx.x * 4 + wid);
    if (node >= n_nodes) return;

    int cnt_all = __builtin_amdgcn_readfirstlane(cursor[node]);
    int cnt = cnt_all < CAP ? cnt_all : CAP;

    float2 acc = make_float2(0.f, 0.f);
    const bool act = lane < 48;

    if (cnt > 0) {
        int idx  = lane < cnt ? lane : cnt - 1;
        int sval = (int)slots[node * CAP + idx];

        int e = 0;
        for (; e + 8 <= cnt; e += 8) {
            int s0 = __builtin_amdgcn_readlane(sval, e);
            int s1 = __builtin_amdgcn_readlane(sval, e + 1);
            int s2 = __builtin_amdgcn_readlane(sval, e + 2);
            int s3 = __builtin_amdgcn_readlane(sval, e + 3);
            int s4 = __builtin_amdgcn_readlane(sval, e + 4);
            int s5 = __builtin_amdgcn_readlane(sval, e + 5);
            int s6 = __builtin_amdgcn_readlane(sval, e + 6);
            int s7 = __builtin_amdgcn_readlane(sval, e + 7);
            if (act) {
                unsigned u0 = xs[s0 * 48 + lane];
                unsigned u1 = xs[s1 * 48 + lane];
                unsigned u2 = xs[s2 * 48 + lane];
                unsigned u3 = xs[s3 * 48 + lane];
                unsigned u4 = xs[s4 * 48 + lane];
                unsigned u5 = xs[s5 * 48 + lane];
                unsigned u6 = xs[s6 * 48 + lane];
                unsigned u7 = xs[s7 * 48 + lane];
                acc.x += __uint_as_float(u0 << 16); acc.y += __uint_as_float(u0 & 0xffff0000u);
                acc.x += __uint_as_float(u1 << 16); acc.y += __uint_as_float(u1 & 0xffff0000u);
                acc.x += __uint_as_float(u2 << 16); acc.y += __uint_as_float(u2 & 0xffff0000u);
                acc.x += __uint_as_float(u3 << 16); acc.y += __uint_as_float(u3 & 0xffff0000u);
                acc.x += __uint_as_float(u4 << 16); acc.y += __uint_as_float(u4 & 0xffff0000u);
                acc.x += __uint_as_float(u5 << 16); acc.y += __uint_as_float(u5 & 0xffff0000u);
                acc.x += __uint_as_float(u6 << 16); acc.y += __uint_as_float(u6 & 0xffff0000u);
                acc.x += __uint_as_float(u7 << 16); acc.y += __uint_as_float(u7 & 0xffff0000u);
            }
        }
        for (; e + 4 <= cnt; e += 4) {
            int s0 = __builtin_amdgcn_readlane(sval, e);
            int s1 = __builtin_amdgcn_readlane(sval, e + 1);
            int s2 = __builtin_amdgcn_readlane(sval, e + 2);
            int s3 = __builtin_amdgcn_readlane(sval, e + 3);
            if (act) {
                unsigned u0 = xs[s0 * 48 + lane];
                unsigned u1 = xs[s1 * 48 + lane];
                unsigned u2 = xs[s2 * 48 + lane];
                unsigned u3 = xs[s3 * 48 + lane];
                acc.x += __uint_as_float(u0 << 16); acc.y += __uint_as_float(u0 & 0xffff0000u);
                acc.x += __uint_as_float(u1 << 16); acc.y += __uint_as_float(u1 & 0xffff0000u);
                acc.x += __uint_as_float(u2 << 16); acc.y += __uint_as_float(u2 & 0xffff0000u);
                acc.x += __uint_as_float(u3 << 16); acc.y += __uint_as_float(u3 & 0xffff0000u);
            }
        }
        for (; e < cnt; ++e) {
            int s0 = __builtin_amdgcn_readlane(sval, e);
            if (act) {
                unsigned u0 = xs[s0 * 48 + lane];
                acc.x += __uint_as_float(u0 << 16); acc.y += __uint_as_float(u0 & 0xffff0000u);
            }
        }
    }

    float sc = rsqrtf((float)(cnt_all < 1 ? 1 : cnt_all));
    if (act) {
        float2 r = make_float2(acc.x * sc, acc.y * sc);
        *(float2*)(out + (size_t)node * D_FEAT + lane * 2) = r;
    }
}

// Fix up edges with dst in-degree > CAP (packed v entries). Adds on gather output.
__global__ void overflow_kernel(const float* __restrict__ x,
                                const int* __restrict__ out_cnt,
                                const int* __restrict__ cursor,
                                const int* __restrict__ ctr,
                                const int* __restrict__ ovf_d,
                                float* __restrict__ out) {
    int count = ctr[0];
    if (count > OVF_CAP) count = OVF_CAP;
    int total = count * 24;
    int stride_t = gridDim.x * blockDim.x;
    for (int i = blockIdx.x * blockDim.x + threadIdx.x; i < total; i += stride_t) {
        int k = i / 24, c = i % 24;
        unsigned pv = (unsigned)ovf_d[k];
        int d = (int)(pv & 0xffffu);
        int s = (int)(pv >> 16);
        int co = out_cnt[s], ci = cursor[d];
        float w = rsqrtf((float)(co < 1 ? 1 : co)) * rsqrtf((float)(ci < 1 ? 1 : ci));
        const float4 v = *(const float4*)(x + (size_t)s * D_FEAT + c * 4);
        float* o = out + (size_t)d * D_FEAT + c * 4;
        unsafeAtomicAdd(o + 0, v.x * w);
        unsafeAtomicAdd(o + 1, v.y * w);
        unsafeAtomicAdd(o + 2, v.z * w);
        unsafeAtomicAdd(o + 3, v.w * w);
    }
}

// ---------------- fallback (round-1 atomic scatter, any size) ----------------

__global__ void degree_kernel(const int* __restrict__ src,
                              const int* __restrict__ dst,
                              int* __restrict__ out_cnt,
                              int* __restrict__ in_cnt, int n_edges) {
    int i = blockIdx.x * blockDim.x + threadIdx.x;
    if (i < n_edges) {
        atomicAdd(&out_cnt[src[i]], 1);
        atomicAdd(&in_cnt[dst[i]], 1);
    }
}

__global__ void scale_kernel(float* __restrict__ osc, float* __restrict__ isc, int n) {
    int i = blockIdx.x * blockDim.x + threadIdx.x;
    if (i < n) {
        int c0 = ((const int*)osc)[i];
        int c1 = ((const int*)isc)[i];
        osc[i] = rsqrtf((float)(c0 < 1 ? 1 : c0));
        isc[i] = rsqrtf((float)(c1 < 1 ? 1 : c1));
    }
}

__global__ void scatter_kernel(const float* __restrict__ x,
                               const int* __restrict__ src,
                               const int* __restrict__ dst,
                               const float* __restrict__ osc,
                               const float* __restrict__ isc,
                               float* __restrict__ out, int n_edges) {
    int idx = blockIdx.x * blockDim.x + threadIdx.x;
    int e = idx / 24, c = idx % 24;
    if (e >= n_edges) return;
    int s = src[e], d = dst[e];
    float w = osc[s] * isc[d];
    const float4 v = *(const float4*)(x + (size_t)s * D_FEAT + c * 4);
    float* o = out + (size_t)d * D_FEAT + c * 4;
    unsafeAtomicAdd(o + 0, v.x * w);
    unsafeAtomicAdd(o + 1, v.y * w);
    unsafeAtomicAdd(o + 2, v.z * w);
    unsafeAtomicAdd(o + 3, v.w * w);
}

// ---------------- launcher ----------------

extern "C" void kernel_launch(void* const* d_in, const int* in_sizes, int n_in,
                              void* d_out, int out_size, void* d_ws, size_t ws_size,
                              hipStream_t stream) {
    const float* x  = (const float*)d_in[0];
    const int* src  = (const int*)d_in[1];
    const int* dst  = (const int*)d_in[2];
    float* out      = (float*)d_out;

    const int n_edges = in_sizes[1];
    const int n_nodes = in_sizes[0] / D_FEAT;

    const int np = (n_nodes + PNODES - 1) / PNODES;
    const int avg = n_edges / (np > 0 ? np : 1);
    const int stride = avg + avg / 4 + 1024;

    const size_t pbuf_words  = (size_t)np * stride;          // dst buffer (uint)
    const size_t pbufs_words = (pbuf_words + 1) / 2;         // src buffer (ushort)

    // ws layout (int32 units):
    int* pcur_d  = (int*)d_ws;            // 256
    int* pcur_s  = pcur_d + 256;          // 256
    int* ctr     = pcur_d + 512;          // 3: ovf_n, povf_n, sovf_n (pad to 1024)
    int* ovf_d   = pcur_d + 1024;         // OVF_CAP (packed v)
    int* povf_d  = ovf_d + OVF_CAP;       // OVF_CAP
    int* sovf_d  = povf_d + OVF_CAP;      // OVF_CAP
    int* out_cnt = sovf_d + OVF_CAP;      // 65536
    int* cursor  = out_cnt + 65536;       // 65536
    unsigned* pbuf_dst = (unsigned*)(cursor + 65536);
    unsigned short* pbuf_src = (unsigned short*)(pbuf_dst + pbuf_words);
    unsigned* xs = pbuf_dst + pbuf_words + pbufs_words;
    unsigned short* slots = (unsigned short*)(xs + (size_t)n_nodes * 48);

    const size_t needed = ((size_t)1024 + 3 * OVF_CAP + 2 * 65536 + pbuf_words +
                           pbufs_words + (size_t)n_nodes * 48 +
                           (size_t)n_nodes * (CAP / 2)) * 4;

    if (ws_size >= needed && n_nodes <= 65536 && np <= NP_MAX) {
        // zero pcur_d, pcur_s, ctr (first 1024 ints)
        hipMemsetAsync(d_ws, 0, 1024 * sizeof(int), stream);

        partition_kernel<<<(n_edges + EPB - 1) / EPB, 256, 0, stream>>>(
            src, dst, n_edges, np, stride, pcur_d, pcur_s,
            pbuf_dst, pbuf_src, ctr, povf_d, sovf_d);

        bin2_kernel<<<np, 256, 0, stream>>>(
            pbuf_dst, pcur_d, stride, n_nodes, cursor, slots, ctr, ovf_d);

        cnt2_kernel<<<np, 256, 0, stream>>>(
            pbuf_src, pcur_s, stride, n_nodes, out_cnt);

        fixup_kernel<<<1, 256, 0, stream>>>(
            ctr, povf_d, sovf_d, ovf_d, cursor, out_cnt);

        const int n_pairs = n_nodes * 48;
        convert_kernel<<<(n_pairs + 255) / 256, 256, 0, stream>>>(
            x, out_cnt, xs, n_pairs);

        gather_kernel<<<(n_nodes + 3) / 4, 256, 0, stream>>>(
            xs, slots, cursor, out, n_nodes);

        overflow_kernel<<<32, 256, 0, stream>>>(
            x, out_cnt, cursor, ctr, ovf_d, out);
    } else {
        // fallback: atomic scatter (round-1 path, any size)
        float* osc = (float*)d_ws;
        float* isc = osc + 65536;
        hipMemsetAsync(d_ws, 0, 2 * 65536 * sizeof(int), stream);
        hipMemsetAsync(d_out, 0, (size_t)out_size * sizeof(float), stream);
        degree_kernel<<<(n_edges + 255) / 256, 256, 0, stream>>>(
            src, dst, (int*)osc, (int*)isc, n_edges);
        scale_kernel<<<(n_nodes + 255) / 256, 256, 0, stream>>>(osc, isc, n_nodes);
        const int total = n_edges * 24;
        scatter_kernel<<<(total + 255) / 256, 256, 0, stream>>>(
            x, src, dst, osc, isc, out, n_edges);
    }
}